// Round 7
// baseline (1154.433 us; speedup 1.0000x reference)
//
#include <hip/hip_runtime.h>
#include <hip/hip_cooperative_groups.h>
#include <math.h>

namespace cg = cooperative_groups;

#define NUM_NODES 50000
#define NUM_EDGES 1600000
#define DIM 128
#define EDGE_DIM 16
#define NKT1 18           // k-tiles (16) for GEMM1 (K=272 padded to 288)
#define NKT2 8            // k-tiles (16) for GEMM2
#define MT 64             // edges per tile
#define CSTRIDE 132       // floats per C-row in LDS (row = 528 B, 16B-aligned)
#define NSCAN 196         // ceil(50000/256)
#define NODE_BLOCKS ((NUM_NODES + 63) / 64)
#define COOP_BLOCKS 1024

typedef short bf16x8 __attribute__((ext_vector_type(8)));
typedef float floatx16 __attribute__((ext_vector_type(16)));
typedef unsigned short ushort4v __attribute__((ext_vector_type(4)));
typedef unsigned short ushort8v __attribute__((ext_vector_type(8)));

__device__ __forceinline__ unsigned short f2b(float f) {
    unsigned u = __builtin_bit_cast(unsigned, f);
    u += 0x7FFFu + ((u >> 16) & 1u);   // round-to-nearest-even
    return (unsigned short)(u >> 16);
}

// ---- ONE cooperative kernel: zero + W repack + h->bf16 + hist + scan +
//      scatter (dst-sorted edge list) ------------------------------------
__global__ __launch_bounds__(256, 8) void prep_all_kernel(
    const float* __restrict__ W1, const float* __restrict__ W2,
    short* __restrict__ W1f, short* __restrict__ W2f,
    const float* __restrict__ h, unsigned short* __restrict__ h_bf,
    const int* __restrict__ src, const int* __restrict__ dst,
    int* __restrict__ counts, int* __restrict__ bsum, int* __restrict__ boffs,
    int* __restrict__ cursor, int2* __restrict__ se_s, float* __restrict__ aggh)
{
    cg::grid_group grid = cg::this_grid();
    __shared__ int sb[256];
    const int tid = threadIdx.x;
    const int gstride = COOP_BLOCKS * 256;
    const int gid0 = blockIdx.x * 256 + tid;

    // ---- phase 0: zero counts + aggh ----
    for (int i = gid0; i < NUM_NODES; i += gstride) counts[i] = 0;
    for (int i = gid0; i < NUM_NODES * (DIM / 4); i += gstride)
        ((float4*)aggh)[i] = make_float4(0.f, 0.f, 0.f, 0.f);
    grid.sync();

    // ---- phase 1: W repack + h conversion + dst histogram ----
    if (gid0 < NKT1 * 4 * 64) {
        int gid = gid0;
        int lane = gid & 63, nb = (gid >> 6) & 3, kt = gid >> 8;
        int n = nb * 32 + (lane & 31);
        int kbase = kt * 16 + (lane >> 5) * 8;
        #pragma unroll
        for (int j = 0; j < 8; ++j) {
            int k = kbase + j;
            W1f[gid * 8 + j] = (k < 272) ? (short)f2b(W1[(size_t)k * DIM + n]) : (short)0;
        }
    } else if (gid0 < NKT1 * 4 * 64 + NKT2 * 4 * 64) {
        int g2 = gid0 - NKT1 * 4 * 64;
        int lane = g2 & 63, nb = (g2 >> 6) & 3, kt = g2 >> 8;
        int n = nb * 32 + (lane & 31);
        int kbase = kt * 16 + (lane >> 5) * 8;
        #pragma unroll
        for (int j = 0; j < 8; ++j)
            W2f[g2 * 8 + j] = (short)f2b(W2[(size_t)(kbase + j) * DIM + n]);
    }
    for (int i = gid0; i < (NUM_NODES * DIM) / 4; i += gstride) {
        float4 v = ((const float4*)h)[i];
        ushort4v o;
        o.x = f2b(v.x); o.y = f2b(v.y); o.z = f2b(v.z); o.w = f2b(v.w);
        ((ushort4v*)h_bf)[i] = o;
    }
    for (int e = gid0; e < NUM_EDGES; e += gstride)
        atomicAdd(&counts[dst[e]], 1);
    grid.sync();

    // ---- phase 2: per-chunk scan; cursor = chunk-exclusive prefix ----
    if (blockIdx.x < NSCAN) {
        int i = blockIdx.x * 256 + tid;
        int v = (i < NUM_NODES) ? counts[i] : 0;
        sb[tid] = v; __syncthreads();
        for (int off = 1; off < 256; off <<= 1) {
            int x = (tid >= off) ? sb[tid - off] : 0;
            __syncthreads(); sb[tid] += x; __syncthreads();
        }
        if (tid == 255) bsum[blockIdx.x] = sb[255];
        if (i < NUM_NODES) cursor[i] = sb[tid] - v;
    }
    grid.sync();

    // ---- phase 3: scan of block sums (block 0) ----
    if (blockIdx.x == 0) {
        int v = (tid < NSCAN) ? bsum[tid] : 0;
        sb[tid] = v; __syncthreads();
        for (int off = 1; off < 256; off <<= 1) {
            int x = (tid >= off) ? sb[tid - off] : 0;
            __syncthreads(); sb[tid] += x; __syncthreads();
        }
        if (tid < NSCAN) boffs[tid] = sb[tid] - v;
    }
    grid.sync();

    // ---- phase 4: add block offsets -> global exclusive cursor ----
    if (blockIdx.x < NSCAN) {
        int i = blockIdx.x * 256 + tid;
        if (i < NUM_NODES) cursor[i] += boffs[blockIdx.x];
    }
    grid.sync();

    // ---- phase 5: scatter (src|dst packed, eid), non-temporal ----
    for (int e = gid0; e < NUM_EDGES; e += gstride) {
        int d = dst[e];
        int p = atomicAdd(&cursor[d], 1);
        unsigned lo = (unsigned)(src[e] | (d << 16));       // node ids < 65536
        long long packed = (long long)((unsigned long long)lo |
                                       ((unsigned long long)(unsigned)e << 32));
        __builtin_nontemporal_store(packed, (long long*)&se_s[p]);
    }
}

// ---- Edge kernel: gather -> GEMM1 -> GELU -> hidden-space segment sum ---
__global__ __launch_bounds__(256, 4) void edge_kernel(
    const unsigned short* __restrict__ h_bf,
    const int2* __restrict__ se_s, const float* __restrict__ ea,
    const short* __restrict__ W1f, const float* __restrict__ pb1,
    float* __restrict__ aggh)
{
    __shared__ __align__(16) short xbuf[36 * 64 * 8];   // 36864 B
    __shared__ int dstl[MT];
    float* cbuf = (float*)xbuf;                         // [64][CSTRIDE] overlay
    float* pbuf = (float*)xbuf;                         // [8][CSTRIDE] partials overlay

    const int tid = threadIdx.x;
    const int lane = tid & 63, wave = tid >> 6;
    const long long base = (long long)blockIdx.x * MT;

    // ---- staging: each thread owns row = lane, chunks kt2 = it*4+wave ----
    {
        int row = lane;
        int2 se = se_s[base + row];
        int sn = se.x & 0xFFFF;
        int dn = ((unsigned)se.x) >> 16;
        if (tid < MT) dstl[tid] = dn;
        const ushort8v* hs = (const ushort8v*)(h_bf + (size_t)sn * DIM);
        const ushort8v* hd = (const ushort8v*)(h_bf + (size_t)dn * DIM);
        #pragma unroll
        for (int it = 0; it < 4; ++it) {
            int kt2 = it * 4 + wave;
            *(ushort8v*)&xbuf[(kt2 * 64 + row) * 8] = hs[kt2];
        }
        #pragma unroll
        for (int it = 0; it < 4; ++it) {
            int kt2 = it * 4 + wave;
            *(ushort8v*)&xbuf[((16 + kt2) * 64 + row) * 8] = hd[kt2];
        }
        // ea (kt2 32,33; fp32->bf16) + zero pad (kt2 34,35)
        if (tid < 128) {
            int r2 = tid >> 1, hc = tid & 1;
            int eid = se_s[base + r2].y;
            const float4* er = (const float4*)(ea + (size_t)eid * EDGE_DIM + hc * 8);
            float4 v0 = er[0], v1 = er[1];
            ushort8v o;
            o[0] = f2b(v0.x); o[1] = f2b(v0.y); o[2] = f2b(v0.z); o[3] = f2b(v0.w);
            o[4] = f2b(v1.x); o[5] = f2b(v1.y); o[6] = f2b(v1.z); o[7] = f2b(v1.w);
            *(ushort8v*)&xbuf[((32 + hc) * 64 + r2) * 8] = o;
        } else {
            int t2 = tid - 128;
            int r2 = t2 >> 1, hc = t2 & 1;
            ushort8v z = {0, 0, 0, 0, 0, 0, 0, 0};
            *(ushort8v*)&xbuf[((34 + hc) * 64 + r2) * 8] = z;
        }
    }
    __syncthreads();

    const int lm = lane & 31, half = lane >> 5;

    // ---- GEMM1: 64 rows x 32 cols per wave ----
    floatx16 acc0 = {}, acc1 = {};
    #pragma unroll
    for (int kt = 0; kt < NKT1; ++kt) {
        bf16x8 a0 = *(const bf16x8*)&xbuf[((kt * 2 + half) * 64 + lm) * 8];
        bf16x8 a1 = *(const bf16x8*)&xbuf[((kt * 2 + half) * 64 + 32 + lm) * 8];
        bf16x8 b  = *(const bf16x8*)(W1f + ((kt * 4 + wave) * 64 + lane) * 8);
        acc0 = __builtin_amdgcn_mfma_f32_32x32x16_bf16(a0, b, acc0, 0, 0, 0);
        acc1 = __builtin_amdgcn_mfma_f32_32x32x16_bf16(a1, b, acc1, 0, 0, 0);
    }
    __syncthreads();   // xbuf reads done before cbuf overlay

    // ---- bias + GELU (tanh form) -> fp32 hidden in cbuf ----
    {
        float bb = pb1[wave * 32 + lm];
        #pragma unroll
        for (int s = 0; s < 2; ++s) {
            const floatx16& A = s ? acc1 : acc0;
            #pragma unroll
            for (int r = 0; r < 16; ++r) {
                int rr = (r & 3) + 8 * (r >> 2) + 4 * half;
                float v = A[r] + bb;
                float u = v * (1.5957691216f + 0.0713548163f * v * v);
                u = fminf(u, 80.f);
                float t = __expf(u);
                float g = v * t * __builtin_amdgcn_rcpf(t + 1.f);
                cbuf[(s * 32 + rr) * CSTRIDE + wave * 32 + lm] = g;
            }
        }
    }
    __syncthreads();

    // ---- phase 1: per-octet register accumulate; mid-octet boundary flush
    int q = tid & 31, g = tid >> 5;    // q: col-quad, g: row-octet
    float4 s4;
    {
        int r0 = g * 8;
        float4 v[8];
        #pragma unroll
        for (int r = 0; r < 8; ++r)
            v[r] = *(const float4*)&cbuf[(r0 + r) * CSTRIDE + q * 4];
        int d[8];
        #pragma unroll
        for (int r = 0; r < 8; ++r) d[r] = dstl[r0 + r];
        s4 = make_float4(0.f, 0.f, 0.f, 0.f);
        int cur = d[0];
        #pragma unroll
        for (int r = 0; r < 8; ++r) {
            s4.x += v[r].x; s4.y += v[r].y; s4.z += v[r].z; s4.w += v[r].w;
            if (r < 7 && d[r + 1] != cur) {          // true boundary (rare)
                float* ap = &aggh[(size_t)cur * DIM + q * 4];
                atomicAdd(ap + 0, s4.x); atomicAdd(ap + 1, s4.y);
                atomicAdd(ap + 2, s4.z); atomicAdd(ap + 3, s4.w);
                s4 = make_float4(0.f, 0.f, 0.f, 0.f);
                cur = d[r + 1];
            }
        }
    }
    __syncthreads();   // all cbuf reads done before pbuf overlay
    *(float4*)&pbuf[g * CSTRIDE + q * 4] = s4;
    __syncthreads();

    // ---- phase 2: 8-deep segmented merge of octet partials per column ----
    if (tid < 128) {
        int col = tid;
        float p[8];
        #pragma unroll
        for (int gg = 0; gg < 8; ++gg) p[gg] = pbuf[gg * CSTRIDE + col];
        int t[8];
        #pragma unroll
        for (int gg = 0; gg < 8; ++gg) t[gg] = dstl[gg * 8 + 7];   // octet trailing node
        float s = 0.f;
        int cur = t[0];
        #pragma unroll
        for (int gg = 0; gg < 8; ++gg) {
            s += p[gg];
            int nxt = (gg == 7) ? -1 : t[gg + 1];
            if (nxt != cur) {
                atomicAdd(&aggh[(size_t)cur * DIM + col], s);
                s = 0.f;
                cur = nxt;
            }
        }
    }
}

// ---- Node kernel: GEMM2 on aggregated hidden + cnt*b2 + residual + LN ---
__global__ __launch_bounds__(256, 4) void node_ln_kernel(
    const float* __restrict__ aggh, const int* __restrict__ counts,
    const short* __restrict__ W2f, const float* __restrict__ pb2,
    const float* __restrict__ h, const float* __restrict__ gamma,
    const float* __restrict__ beta, float* __restrict__ out)
{
    __shared__ __align__(16) float sbuf[64 * CSTRIDE];   // 33792 B (abuf overlay)
    __shared__ int cntl[64];
    short* abuf = (short*)sbuf;

    const int tid = threadIdx.x;
    const int n0 = blockIdx.x * 64;

    if (tid < 64) {
        int node = n0 + tid;
        cntl[tid] = (node < NUM_NODES) ? counts[node] : 0;
    }
    #pragma unroll
    for (int it = 0; it < 4; ++it) {
        int g = it * 256 + tid;
        int kt2 = g >> 6, row = g & 63;
        int node = n0 + row;
        ushort8v o = {0, 0, 0, 0, 0, 0, 0, 0};
        if (node < NUM_NODES) {
            const float4* p = (const float4*)(aggh + (size_t)node * DIM + kt2 * 8);
            float4 v0 = p[0], v1 = p[1];
            o[0] = f2b(v0.x); o[1] = f2b(v0.y); o[2] = f2b(v0.z); o[3] = f2b(v0.w);
            o[4] = f2b(v1.x); o[5] = f2b(v1.y); o[6] = f2b(v1.z); o[7] = f2b(v1.w);
        }
        *(ushort8v*)&abuf[(kt2 * 64 + row) * 8] = o;
    }
    __syncthreads();

    const int lane = tid & 63, wave = tid >> 6;
    const int lm = lane & 31, half = lane >> 5;

    floatx16 acc0 = {}, acc1 = {};
    #pragma unroll
    for (int kt = 0; kt < NKT2; ++kt) {
        bf16x8 a0 = *(const bf16x8*)&abuf[((kt * 2 + half) * 64 + lm) * 8];
        bf16x8 a1 = *(const bf16x8*)&abuf[((kt * 2 + half) * 64 + 32 + lm) * 8];
        bf16x8 b  = *(const bf16x8*)(W2f + ((kt * 4 + wave) * 64 + lane) * 8);
        acc0 = __builtin_amdgcn_mfma_f32_32x32x16_bf16(a0, b, acc0, 0, 0, 0);
        acc1 = __builtin_amdgcn_mfma_f32_32x32x16_bf16(a1, b, acc1, 0, 0, 0);
    }
    __syncthreads();   // abuf reads done before sbuf overlay

    float bb2 = pb2[wave * 32 + lm];
    #pragma unroll
    for (int s = 0; s < 2; ++s) {
        const floatx16& A = s ? acc1 : acc0;
        #pragma unroll
        for (int r = 0; r < 16; ++r) {
            int rr = (r & 3) + 8 * (r >> 2) + 4 * half;
            int row = s * 32 + rr;
            sbuf[row * CSTRIDE + wave * 32 + lm] = A[r] + (float)cntl[row] * bb2;
        }
    }
    __syncthreads();

    // LayerNorm: 4 lanes per row, 32 cols each
    {
        int row = tid >> 2, q = tid & 3;
        int node = n0 + row;
        if (node < NUM_NODES) {
            float4 xv[8];
            float s = 0.f, ss = 0.f;
            const float4* hp = (const float4*)(h + (size_t)node * DIM + q * 32);
            #pragma unroll
            for (int i = 0; i < 8; ++i) {
                float4 c = *(const float4*)&sbuf[row * CSTRIDE + q * 32 + i * 4];
                float4 hh = hp[i];
                float4 x;
                x.x = c.x + hh.x; x.y = c.y + hh.y; x.z = c.z + hh.z; x.w = c.w + hh.w;
                xv[i] = x;
                s  += x.x + x.y + x.z + x.w;
                ss += x.x * x.x + x.y * x.y + x.z * x.z + x.w * x.w;
            }
            s  += __shfl_xor(s, 1, 64);  s  += __shfl_xor(s, 2, 64);
            ss += __shfl_xor(ss, 1, 64); ss += __shfl_xor(ss, 2, 64);
            float mu = s * (1.f / DIM);
            float var = ss * (1.f / DIM) - mu * mu;
            float rs = rsqrtf(var + 1e-5f);
            const float4* gp = (const float4*)(gamma + q * 32);
            const float4* bp = (const float4*)(beta + q * 32);
            float4* op = (float4*)(out + (size_t)node * DIM + q * 32);
            #pragma unroll
            for (int i = 0; i < 8; ++i) {
                float4 g4 = gp[i], b4 = bp[i], o;
                o.x = (xv[i].x - mu) * rs * g4.x + b4.x;
                o.y = (xv[i].y - mu) * rs * g4.y + b4.y;
                o.z = (xv[i].z - mu) * rs * g4.z + b4.z;
                o.w = (xv[i].w - mu) * rs * g4.w + b4.w;
                op[i] = o;
            }
        }
    }
}

extern "C" void kernel_launch(void* const* d_in, const int* in_sizes, int n_in,
                              void* d_out, int out_size, void* d_ws, size_t ws_size,
                              hipStream_t stream)
{
    const float* h     = (const float*)d_in[0];
    const int*   src   = (const int*)d_in[1];
    const int*   dst   = (const int*)d_in[2];
    const float* ea    = (const float*)d_in[3];
    const float* W1    = (const float*)d_in[4];
    const float* pb1   = (const float*)d_in[5];
    const float* W2    = (const float*)d_in[6];
    const float* pb2   = (const float*)d_in[7];
    const float* gamma = (const float*)d_in[8];
    const float* beta  = (const float*)d_in[9];
    float* out = (float*)d_out;

    char* ws = (char*)d_ws;
    short* W1f   = (short*)ws;                        //        0 (73728 B)
    short* W2f   = (short*)(ws + 73728);              //  (32768 B)
    int* counts  = (int*)(ws + 106496);               //  (200000 B)
    int* cursor  = (int*)(ws + 306496);               //  (200000 B)
    int* bsum    = (int*)(ws + 506496);               //  (1024 B)
    int* boffs   = (int*)(ws + 507520);               //  (1024 B)
    int2* se_s   = (int2*)(ws + 508544);              //  (12800000 B)
    unsigned short* h_bf = (unsigned short*)(ws + 19708544);   // (12800000 B)
    float* aggh  = (float*)(ws + 32508544);           //  (25600000 B) -> 58108544

    void* cargs[] = {
        (void*)&W1, (void*)&W2, (void*)&W1f, (void*)&W2f,
        (void*)&h, (void*)&h_bf, (void*)&src, (void*)&dst,
        (void*)&counts, (void*)&bsum, (void*)&boffs,
        (void*)&cursor, (void*)&se_s, (void*)&aggh
    };
    hipLaunchCooperativeKernel((const void*)prep_all_kernel,
                               dim3(COOP_BLOCKS), dim3(256), cargs, 0, stream);
    edge_kernel<<<NUM_EDGES / MT, 256, 0, stream>>>(h_bf, se_s, ea, W1f, pb1, aggh);
    node_ln_kernel<<<NODE_BLOCKS, 256, 0, stream>>>(aggh, counts, W2f, pb2,
                                                    h, gamma, beta, out);
}

// Round 8
// 618.790 us; speedup vs baseline: 1.8656x; 1.8656x over previous
//
#include <hip/hip_runtime.h>
#include <math.h>

#define NUM_NODES 50000
#define NUM_EDGES 1600000
#define DIM 128
#define EDGE_DIM 16
#define NKT1 17           // k-tiles (16) for GEMM1: K=272 = 17*16 exactly
#define NKT2 8            // k-tiles (16) for GEMM2
#define MT 64             // edges per tile
#define CSTRIDE 132       // floats per C-row in LDS (row = 528 B, 16B-aligned)
#define NSCAN 196         // ceil(50000/256)
#define NODE_BLOCKS ((NUM_NODES + 63) / 64)

// setup_kernel block map
#define SB_W     25                    // 6400 fragment-lanes / 256
#define SB_HCONV (SB_W + 6250)         // 1.6M float4 / 256
#define SB_HIST  (SB_HCONV + 6250)     // 1.6M edges / 256
#define SB_ZERO  (SB_HIST + 1563)      // 1.6M float4, 4 per thread

typedef short bf16x8 __attribute__((ext_vector_type(8)));
typedef float floatx16 __attribute__((ext_vector_type(16)));
typedef unsigned short ushort4v __attribute__((ext_vector_type(4)));
typedef unsigned short ushort8v __attribute__((ext_vector_type(8)));

__device__ __forceinline__ unsigned short f2b(float f) {
    unsigned u = __builtin_bit_cast(unsigned, f);
    u += 0x7FFFu + ((u >> 16) & 1u);   // round-to-nearest-even
    return (unsigned short)(u >> 16);
}

// ---- fused setup: W repack + h->bf16 + dst histogram + zero aggh --------
__global__ void setup_kernel(const float* __restrict__ W1, const float* __restrict__ W2,
                             short* __restrict__ W1f, short* __restrict__ W2f,
                             const float* __restrict__ h, unsigned short* __restrict__ h_bf,
                             const int* __restrict__ dst, int* __restrict__ counts,
                             float* __restrict__ aggh)
{
    int b = blockIdx.x, tid = threadIdx.x;
    if (b < SB_W) {
        int gid = b * 256 + tid;
        if (gid < NKT1 * 4 * 64) {                    // 4352 W1 fragment-lanes
            int lane = gid & 63, nb = (gid >> 6) & 3, kt = gid >> 8;
            int n = nb * 32 + (lane & 31);
            int kbase = kt * 16 + (lane >> 5) * 8;
            #pragma unroll
            for (int j = 0; j < 8; ++j)
                W1f[gid * 8 + j] = (short)f2b(W1[(size_t)(kbase + j) * DIM + n]);
        } else if (gid < NKT1 * 4 * 64 + NKT2 * 4 * 64) {
            int g2 = gid - NKT1 * 4 * 64;
            int lane = g2 & 63, nb = (g2 >> 6) & 3, kt = g2 >> 8;
            int n = nb * 32 + (lane & 31);
            int kbase = kt * 16 + (lane >> 5) * 8;
            #pragma unroll
            for (int j = 0; j < 8; ++j)
                W2f[g2 * 8 + j] = (short)f2b(W2[(size_t)(kbase + j) * DIM + n]);
        }
    } else if (b < SB_HCONV) {
        int t = (b - SB_W) * 256 + tid;   // 4 floats each
        float4 v = ((const float4*)h)[t];
        ushort4v o;
        o.x = f2b(v.x); o.y = f2b(v.y); o.z = f2b(v.z); o.w = f2b(v.w);
        ((ushort4v*)h_bf)[t] = o;
    } else if (b < SB_HIST) {
        int e = (b - SB_HCONV) * 256 + tid;
        atomicAdd(&counts[dst[e]], 1);
    } else {
        int i0 = ((b - SB_HIST) * 256 + tid) * 4;
        float4 z = make_float4(0.f, 0.f, 0.f, 0.f);
        #pragma unroll
        for (int j = 0; j < 4; ++j)
            if (i0 + j < NUM_NODES * (DIM / 4)) ((float4*)aggh)[i0 + j] = z;
    }
}

// ---- scan pass A: per-chunk block sums ----------------------------------
__global__ void scanA_kernel(const int* __restrict__ counts, int* __restrict__ bsum) {
    __shared__ int sb[256];
    int t = threadIdx.x, i = blockIdx.x * 256 + t;
    int v = (i < NUM_NODES) ? counts[i] : 0;
    sb[t] = v; __syncthreads();
    for (int off = 1; off < 256; off <<= 1) {
        int x = (t >= off) ? sb[t - off] : 0;
        __syncthreads(); sb[t] += x; __syncthreads();
    }
    if (t == 255) bsum[blockIdx.x] = sb[255];
}

// ---- scan pass BC: chunk scan + inline block-offset reduction -----------
__global__ void scanBC_kernel(const int* __restrict__ counts, const int* __restrict__ bsum,
                              int* __restrict__ cursor) {
    __shared__ int sb[256];
    int t = threadIdx.x, b = blockIdx.x, i = b * 256 + t;
    int v = (i < NUM_NODES) ? counts[i] : 0;
    sb[t] = v; __syncthreads();
    for (int off = 1; off < 256; off <<= 1) {
        int x = (t >= off) ? sb[t - off] : 0;
        __syncthreads(); sb[t] += x; __syncthreads();
    }
    int myexcl = sb[t] - v;
    __syncthreads();
    // boff = sum of bsum[0..b-1]
    sb[t] = (t < b && t < NSCAN) ? bsum[t] : 0;
    __syncthreads();
    for (int off = 128; off > 0; off >>= 1) {
        if (t < off) sb[t] += sb[t + off];
        __syncthreads();
    }
    if (i < NUM_NODES) cursor[i] = sb[0] + myexcl;   // global exclusive offset
}

// ---- scatter (src|dst packed, eid) into dst-sorted order ----------------
__global__ void scatter_kernel(const int* __restrict__ src, const int* __restrict__ dst,
                               int* __restrict__ cursor, int2* __restrict__ se_s)
{
    int e = blockIdx.x * 256 + threadIdx.x;
    int d = dst[e];
    int p = atomicAdd(&cursor[d], 1);
    se_s[p] = make_int2(src[e] | (d << 16), e);   // node ids < 65536
}

// ---- Edge kernel: gather -> GEMM1 -> GELU -> hidden-space segment sum ---
__global__ __launch_bounds__(256, 4) void edge_kernel(
    const unsigned short* __restrict__ h_bf,
    const int2* __restrict__ se_s, const float* __restrict__ ea,
    const short* __restrict__ W1f, const float* __restrict__ pb1,
    float* __restrict__ aggh)
{
    __shared__ __align__(16) short xbuf[34 * 64 * 8];   // 34816 B (K=272)
    __shared__ int dstl[MT];
    float* cbuf = (float*)xbuf;                         // [64][CSTRIDE] overlay (33792 B)
    float* pbuf = (float*)xbuf;                         // [8][CSTRIDE] partials overlay

    const int tid = threadIdx.x;
    const int lane = tid & 63, wave = tid >> 6;
    const long long base = (long long)blockIdx.x * MT;

    // ---- staging: each thread owns row = lane, chunks kt2 = it*4+wave ----
    {
        int row = lane;
        int2 se = se_s[base + row];
        int sn = se.x & 0xFFFF;
        int dn = ((unsigned)se.x) >> 16;
        if (tid < MT) dstl[tid] = dn;
        const ushort8v* hs = (const ushort8v*)(h_bf + (size_t)sn * DIM);
        const ushort8v* hd = (const ushort8v*)(h_bf + (size_t)dn * DIM);
        #pragma unroll
        for (int it = 0; it < 4; ++it) {
            int kt2 = it * 4 + wave;
            *(ushort8v*)&xbuf[(kt2 * 64 + row) * 8] = hs[kt2];
        }
        #pragma unroll
        for (int it = 0; it < 4; ++it) {
            int kt2 = it * 4 + wave;
            *(ushort8v*)&xbuf[((16 + kt2) * 64 + row) * 8] = hd[kt2];
        }
        // ea (kt2 32,33; fp32->bf16). K=272 exactly -> no zero pad.
        if (tid < 128) {
            int r2 = tid >> 1, hc = tid & 1;
            int eid = se_s[base + r2].y;
            const float4* er = (const float4*)(ea + (size_t)eid * EDGE_DIM + hc * 8);
            float4 v0 = er[0], v1 = er[1];
            ushort8v o;
            o[0] = f2b(v0.x); o[1] = f2b(v0.y); o[2] = f2b(v0.z); o[3] = f2b(v0.w);
            o[4] = f2b(v1.x); o[5] = f2b(v1.y); o[6] = f2b(v1.z); o[7] = f2b(v1.w);
            *(ushort8v*)&xbuf[((32 + hc) * 64 + r2) * 8] = o;
        }
    }
    __syncthreads();

    const int lm = lane & 31, half = lane >> 5;

    // ---- GEMM1: 64 rows x 32 cols per wave, 17 k-tiles ----
    floatx16 acc0 = {}, acc1 = {};
    #pragma unroll
    for (int kt = 0; kt < NKT1; ++kt) {
        bf16x8 a0 = *(const bf16x8*)&xbuf[((kt * 2 + half) * 64 + lm) * 8];
        bf16x8 a1 = *(const bf16x8*)&xbuf[((kt * 2 + half) * 64 + 32 + lm) * 8];
        bf16x8 b  = *(const bf16x8*)(W1f + ((kt * 4 + wave) * 64 + lane) * 8);
        acc0 = __builtin_amdgcn_mfma_f32_32x32x16_bf16(a0, b, acc0, 0, 0, 0);
        acc1 = __builtin_amdgcn_mfma_f32_32x32x16_bf16(a1, b, acc1, 0, 0, 0);
    }
    __syncthreads();   // xbuf reads done before cbuf overlay

    // ---- bias + GELU (tanh form) -> fp32 hidden in cbuf ----
    {
        float bb = pb1[wave * 32 + lm];
        #pragma unroll
        for (int s = 0; s < 2; ++s) {
            const floatx16& A = s ? acc1 : acc0;
            #pragma unroll
            for (int r = 0; r < 16; ++r) {
                int rr = (r & 3) + 8 * (r >> 2) + 4 * half;
                float v = A[r] + bb;
                float u = v * (1.5957691216f + 0.0713548163f * v * v);
                u = fminf(u, 80.f);
                float t = __expf(u);
                float g = v * t * __builtin_amdgcn_rcpf(t + 1.f);
                cbuf[(s * 32 + rr) * CSTRIDE + wave * 32 + lm] = g;
            }
        }
    }
    __syncthreads();

    // ---- phase 1: per-octet register accumulate; mid-octet boundary flush
    int q = tid & 31, g = tid >> 5;    // q: col-quad, g: row-octet
    float4 s4;
    {
        int r0 = g * 8;
        float4 v[8];
        #pragma unroll
        for (int r = 0; r < 8; ++r)
            v[r] = *(const float4*)&cbuf[(r0 + r) * CSTRIDE + q * 4];
        int d[8];
        #pragma unroll
        for (int r = 0; r < 8; ++r) d[r] = dstl[r0 + r];
        s4 = make_float4(0.f, 0.f, 0.f, 0.f);
        int cur = d[0];
        #pragma unroll
        for (int r = 0; r < 8; ++r) {
            s4.x += v[r].x; s4.y += v[r].y; s4.z += v[r].z; s4.w += v[r].w;
            if (r < 7 && d[r + 1] != cur) {          // true boundary (rare)
                float* ap = &aggh[(size_t)cur * DIM + q * 4];
                atomicAdd(ap + 0, s4.x); atomicAdd(ap + 1, s4.y);
                atomicAdd(ap + 2, s4.z); atomicAdd(ap + 3, s4.w);
                s4 = make_float4(0.f, 0.f, 0.f, 0.f);
                cur = d[r + 1];
            }
        }
    }
    __syncthreads();   // all cbuf reads done before pbuf overlay
    *(float4*)&pbuf[g * CSTRIDE + q * 4] = s4;
    __syncthreads();

    // ---- phase 2: 8-deep segmented merge of octet partials per column ----
    if (tid < 128) {
        int col = tid;
        float p[8];
        #pragma unroll
        for (int gg = 0; gg < 8; ++gg) p[gg] = pbuf[gg * CSTRIDE + col];
        int t[8];
        #pragma unroll
        for (int gg = 0; gg < 8; ++gg) t[gg] = dstl[gg * 8 + 7];   // octet trailing node
        float s = 0.f;
        int cur = t[0];
        #pragma unroll
        for (int gg = 0; gg < 8; ++gg) {
            s += p[gg];
            int nxt = (gg == 7) ? -1 : t[gg + 1];
            if (nxt != cur) {
                atomicAdd(&aggh[(size_t)cur * DIM + col], s);
                s = 0.f;
                cur = nxt;
            }
        }
    }
}

// ---- Node kernel: GEMM2 on aggregated hidden + cnt*b2 + residual + LN ---
__global__ __launch_bounds__(256, 4) void node_ln_kernel(
    const float* __restrict__ aggh, const int* __restrict__ counts,
    const short* __restrict__ W2f, const float* __restrict__ pb2,
    const float* __restrict__ h, const float* __restrict__ gamma,
    const float* __restrict__ beta, float* __restrict__ out)
{
    __shared__ __align__(16) float sbuf[64 * CSTRIDE];   // 33792 B (abuf overlay)
    __shared__ int cntl[64];
    short* abuf = (short*)sbuf;

    const int tid = threadIdx.x;
    const int n0 = blockIdx.x * 64;

    if (tid < 64) {
        int node = n0 + tid;
        cntl[tid] = (node < NUM_NODES) ? counts[node] : 0;
    }
    #pragma unroll
    for (int it = 0; it < 4; ++it) {
        int g = it * 256 + tid;
        int kt2 = g >> 6, row = g & 63;
        int node = n0 + row;
        ushort8v o = {0, 0, 0, 0, 0, 0, 0, 0};
        if (node < NUM_NODES) {
            const float4* p = (const float4*)(aggh + (size_t)node * DIM + kt2 * 8);
            float4 v0 = p[0], v1 = p[1];
            o[0] = f2b(v0.x); o[1] = f2b(v0.y); o[2] = f2b(v0.z); o[3] = f2b(v0.w);
            o[4] = f2b(v1.x); o[5] = f2b(v1.y); o[6] = f2b(v1.z); o[7] = f2b(v1.w);
        }
        *(ushort8v*)&abuf[(kt2 * 64 + row) * 8] = o;
    }
    __syncthreads();

    const int lane = tid & 63, wave = tid >> 6;
    const int lm = lane & 31, half = lane >> 5;

    floatx16 acc0 = {}, acc1 = {};
    #pragma unroll
    for (int kt = 0; kt < NKT2; ++kt) {
        bf16x8 a0 = *(const bf16x8*)&abuf[((kt * 2 + half) * 64 + lm) * 8];
        bf16x8 a1 = *(const bf16x8*)&abuf[((kt * 2 + half) * 64 + 32 + lm) * 8];
        bf16x8 b  = *(const bf16x8*)(W2f + ((kt * 4 + wave) * 64 + lane) * 8);
        acc0 = __builtin_amdgcn_mfma_f32_32x32x16_bf16(a0, b, acc0, 0, 0, 0);
        acc1 = __builtin_amdgcn_mfma_f32_32x32x16_bf16(a1, b, acc1, 0, 0, 0);
    }
    __syncthreads();   // abuf reads done before sbuf overlay

    float bb2 = pb2[wave * 32 + lm];
    #pragma unroll
    for (int s = 0; s < 2; ++s) {
        const floatx16& A = s ? acc1 : acc0;
        #pragma unroll
        for (int r = 0; r < 16; ++r) {
            int rr = (r & 3) + 8 * (r >> 2) + 4 * half;
            int row = s * 32 + rr;
            sbuf[row * CSTRIDE + wave * 32 + lm] = A[r] + (float)cntl[row] * bb2;
        }
    }
    __syncthreads();

    // LayerNorm: 4 lanes per row, 32 cols each
    {
        int row = tid >> 2, q = tid & 3;
        int node = n0 + row;
        if (node < NUM_NODES) {
            float4 xv[8];
            float s = 0.f, ss = 0.f;
            const float4* hp = (const float4*)(h + (size_t)node * DIM + q * 32);
            #pragma unroll
            for (int i = 0; i < 8; ++i) {
                float4 c = *(const float4*)&sbuf[row * CSTRIDE + q * 32 + i * 4];
                float4 hh = hp[i];
                float4 x;
                x.x = c.x + hh.x; x.y = c.y + hh.y; x.z = c.z + hh.z; x.w = c.w + hh.w;
                xv[i] = x;
                s  += x.x + x.y + x.z + x.w;
                ss += x.x * x.x + x.y * x.y + x.z * x.z + x.w * x.w;
            }
            s  += __shfl_xor(s, 1, 64);  s  += __shfl_xor(s, 2, 64);
            ss += __shfl_xor(ss, 1, 64); ss += __shfl_xor(ss, 2, 64);
            float mu = s * (1.f / DIM);
            float var = ss * (1.f / DIM) - mu * mu;
            float rs = rsqrtf(var + 1e-5f);
            const float4* gp = (const float4*)(gamma + q * 32);
            const float4* bp = (const float4*)(beta + q * 32);
            float4* op = (float4*)(out + (size_t)node * DIM + q * 32);
            #pragma unroll
            for (int i = 0; i < 8; ++i) {
                float4 g4 = gp[i], b4 = bp[i], o;
                o.x = (xv[i].x - mu) * rs * g4.x + b4.x;
                o.y = (xv[i].y - mu) * rs * g4.y + b4.y;
                o.z = (xv[i].z - mu) * rs * g4.z + b4.z;
                o.w = (xv[i].w - mu) * rs * g4.w + b4.w;
                op[i] = o;
            }
        }
    }
}

extern "C" void kernel_launch(void* const* d_in, const int* in_sizes, int n_in,
                              void* d_out, int out_size, void* d_ws, size_t ws_size,
                              hipStream_t stream)
{
    const float* h     = (const float*)d_in[0];
    const int*   src   = (const int*)d_in[1];
    const int*   dst   = (const int*)d_in[2];
    const float* ea    = (const float*)d_in[3];
    const float* W1    = (const float*)d_in[4];
    const float* pb1   = (const float*)d_in[5];
    const float* W2    = (const float*)d_in[6];
    const float* pb2   = (const float*)d_in[7];
    const float* gamma = (const float*)d_in[8];
    const float* beta  = (const float*)d_in[9];
    float* out = (float*)d_out;

    char* ws = (char*)d_ws;
    short* W1f   = (short*)ws;                        //        0 (69632 B: 17*4*64*8*2)
    short* W2f   = (short*)(ws + 69632);              //  (32768 B)
    int* counts  = (int*)(ws + 102400);               //  (200000 B)
    int* cursor  = (int*)(ws + 302400);               //  (200000 B)
    int* bsum    = (int*)(ws + 502400);               //  (1024 B)
    int2* se_s   = (int2*)(ws + 503424);              //  (12800000 B)
    unsigned short* h_bf = (unsigned short*)(ws + 13303424);   // (12800000 B)
    float* aggh  = (float*)(ws + 26103424);           //  (25600000 B) -> 51703424

    hipMemsetAsync(counts, 0, NUM_NODES * sizeof(int), stream);
    setup_kernel<<<SB_ZERO, 256, 0, stream>>>(W1, W2, W1f, W2f, h, h_bf, dst,
                                              counts, aggh);
    scanA_kernel<<<NSCAN, 256, 0, stream>>>(counts, bsum);
    scanBC_kernel<<<NSCAN, 256, 0, stream>>>(counts, bsum, cursor);
    scatter_kernel<<<NUM_EDGES / 256, 256, 0, stream>>>(src, dst, cursor, se_s);
    edge_kernel<<<NUM_EDGES / MT, 256, 0, stream>>>(h_bf, se_s, ea, W1f, pb1, aggh);
    node_ln_kernel<<<NODE_BLOCKS, 256, 0, stream>>>(aggh, counts, W2f, pb2,
                                                    h, gamma, beta, out);
}